// Round 8
// baseline (207.702 us; speedup 1.0000x reference)
//
#include <hip/hip_runtime.h>
#include <hip/hip_bf16.h>
#include <stdint.h>

#define HIDDEN  1024
#define FFN_DIM 2048
#define NEXP    8
#define NTOK    2048          // B*S
#define MAXROWS 5120          // sum of 128-padded per-expert counts

typedef short bf16x8 __attribute__((ext_vector_type(8)));
typedef float f32x4  __attribute__((ext_vector_type(4)));

// ---------------- ws layout (bytes) ----------------
static const size_t OFF_CNT  = 0;                         // 8 ints
static const size_t OFF_BASE = 64;                        // 9 ints
static const size_t OFF_TOK  = 128;                       // 8*2048 ints
static const size_t OFF_WGT  = OFF_TOK + (size_t)NEXP*NTOK*4;
static const size_t OFF_XBF  = 131328;                    // 256-aligned
static const size_t XBF_B    = (size_t)NTOK*HIDDEN*2;
static const size_t OFF_H    = OFF_XBF + XBF_B;
static const size_t H_B      = (size_t)MAXROWS*FFN_DIM*2;
static const size_t WS_NEED  = OFF_H + H_B;               // ~25 MB

__device__ __forceinline__ unsigned short f2bf(float f) {
  union { float f; unsigned u; } a; a.f = f;
  unsigned r = a.u + 0x7fff + ((a.u >> 16) & 1);          // RTN-even
  return (unsigned short)(r >> 16);
}

// 8 fp32 -> bf16x8 via packed cvt (memory order preserved)
__device__ __forceinline__ bf16x8 cvt8b(float4 a, float4 b) {
  union { uint4 u; bf16x8 v; } r;
  asm("v_cvt_pk_bf16_f32 %0, %1, %2" : "=v"(r.u.x) : "v"(a.x), "v"(a.y));
  asm("v_cvt_pk_bf16_f32 %0, %1, %2" : "=v"(r.u.y) : "v"(a.z), "v"(a.w));
  asm("v_cvt_pk_bf16_f32 %0, %1, %2" : "=v"(r.u.z) : "v"(b.x), "v"(b.y));
  asm("v_cvt_pk_bf16_f32 %0, %1, %2" : "=v"(r.u.w) : "v"(b.z), "v"(b.w));
  return r.v;
}

__device__ __forceinline__ void ld_g2l16(const void* gsrc, void* ldst) {
  __builtin_amdgcn_global_load_lds(
      (const __attribute__((address_space(1))) unsigned int*)gsrc,
      (__attribute__((address_space(3))) unsigned int*)ldst, 16, 0, 0);
}

// ---------------- Router: fp32-exact logits, top-2, renorm weights, bins; fused x->bf16 --------
__global__ __launch_bounds__(256) void router_kernel(
    const float* __restrict__ x, const float* __restrict__ gw,
    float* __restrict__ logits, int* __restrict__ cnt,
    int* __restrict__ tok, float* __restrict__ wgt,
    unsigned short* __restrict__ xbf)
{
  const int t   = blockIdx.x;
  const int tid = threadIdx.x;
  float4 xv = ((const float4*)(x + (size_t)t * HIDDEN))[tid];
  if (xbf) {
    ushort4 o;
    o.x = f2bf(xv.x); o.y = f2bf(xv.y); o.z = f2bf(xv.z); o.w = f2bf(xv.w);
    ((ushort4*)(xbf + (size_t)t * HIDDEN))[tid] = o;
  }
  float p[NEXP];
#pragma unroll
  for (int e = 0; e < NEXP; ++e) {
    float4 gv = ((const float4*)(gw + (size_t)e * HIDDEN))[tid];
    p[e] = xv.x * gv.x + xv.y * gv.y + xv.z * gv.z + xv.w * gv.w;
  }
#pragma unroll
  for (int e = 0; e < NEXP; ++e) {
#pragma unroll
    for (int off = 32; off > 0; off >>= 1)
      p[e] += __shfl_down(p[e], off, 64);
  }
  __shared__ float red[4][NEXP];
  const int wv = tid >> 6, ln = tid & 63;
  if (ln == 0) {
#pragma unroll
    for (int e = 0; e < NEXP; ++e) red[wv][e] = p[e];
  }
  __syncthreads();
  if (tid == 0) {
    float l[NEXP];
#pragma unroll
    for (int e = 0; e < NEXP; ++e) {
      l[e] = red[0][e] + red[1][e] + red[2][e] + red[3][e];
      logits[(size_t)t * NEXP + e] = l[e];
    }
    int i0 = 0;
#pragma unroll
    for (int e = 1; e < NEXP; ++e) if (l[e] > l[i0]) i0 = e;
    int i1 = (i0 == 0) ? 1 : 0;
#pragma unroll
    for (int e = 0; e < NEXP; ++e) if (e != i0 && l[e] > l[i1]) i1 = e;
    float w0 = 1.f / (1.f + expf(l[i1] - l[i0]));
    float w1 = 1.f - w0;
    int s0 = atomicAdd(&cnt[i0], 1);
    tok[i0 * NTOK + s0] = t;  wgt[i0 * NTOK + s0] = w0;
    int s1 = atomicAdd(&cnt[i1], 1);
    tok[i1 * NTOK + s1] = t;  wgt[i1 * NTOK + s1] = w1;
  }
}

// ---------------- 128-padded per-expert row bases ----------------
__global__ void prefix_kernel(const int* __restrict__ cnt, int* __restrict__ base) {
  if (threadIdx.x == 0 && blockIdx.x == 0) {
    int b = 0;
#pragma unroll
    for (int e = 0; e < NEXP; ++e) { base[e] = b; b += ((cnt[e] + 127) >> 7) << 7; }
    base[NEXP] = b;
  }
}

// ---------------- GEMM1: H = silu(X W1^T) * (X W3^T) ------------------------------------------
// M=128 x N=64 x BK=64, 256 thr (4 waves: 2M x 2N). ALL staging via g2l.
// Pipeline: W1/W3 double-buffered, W(k+1) issued at top of step k, counted vmcnt(8)
// (never 0 mid-loop); X single-buffered (L2-hot). Raw s_barrier (no vmcnt(0) drain).
// X: bf16 LDS [128 rows][8 u16B], phys unit u holds global unit u^(r&7).
// W: fp32 LDS [64 rows][16 u16B], phys unit u holds global fp32-unit u^(r&15);
// fragment (8 fp32 = units {2u,2u+1}) -> 2 ds_read_b128 + cvt8b on the read path.
__global__ __launch_bounds__(256, 2) void gemm1_kernel(
    const unsigned short* __restrict__ xbf,   // [NTOK][HIDDEN] bf16
    const float* __restrict__ w1f,            // [E][FFN][HIDDEN] fp32
    const float* __restrict__ w3f,
    const int* __restrict__ cnt, const int* __restrict__ base,
    const int* __restrict__ tok,
    unsigned short* __restrict__ H)           // [MAXROWS][FFN] bf16
{
  // XCD-grouped: expert = bid%8 (one expert per XCD), mt fastest within XCD.
  const int bid  = blockIdx.x;
  const int e    = bid & 7;
  const int slot = bid >> 3;            // 0..511
  const int mt   = slot & 15;           // 128-row token tile
  const int nt   = slot >> 4;           // 0..31, 64-col ffn tile
  const int n = cnt[e];
  if (mt * 128 >= n) return;
  const int t = threadIdx.x;
  const int w = t >> 6, l = t & 63;

  __shared__ unsigned short Xs[128 * 64];    // 16 KB bf16, single buffer
  __shared__ float W1s[2][64 * 64];          // 2 x 16 KB fp32
  __shared__ float W3s[2][64 * 64];          // 2 x 16 KB fp32

  // X staging: call c covers rows c*32..c*32+31; thread row = c*32 + (t>>3)
  const int xr   = t >> 3;                        // 0..31
  const int xkey = ((t & 7) ^ (xr & 7)) << 3;     // pre-swizzled k-elem offset
  const unsigned short* xp[4];
#pragma unroll
  for (int c = 0; c < 4; ++c) {
    int row = min(mt * 128 + c * 32 + xr, n - 1);
    xp[c] = xbf + (size_t)tok[e * NTOK + row] * HIDDEN + xkey;
  }

  // W staging: call c covers rows c*16..c*16+15; thread row = c*16 + (t>>4)
  const int wr   = t >> 4;                        // 0..15
  const int wkey = ((t & 15) ^ wr) << 2;          // pre-swizzled fp32-elem offset
  const float* w1p = w1f + (size_t)e * FFN_DIM * HIDDEN + ((size_t)nt * 64 + wr) * HIDDEN + wkey;
  const float* w3p = w3f + (size_t)e * FFN_DIM * HIDDEN + ((size_t)nt * 64 + wr) * HIDDEN + wkey;

  f32x4 acc1[4][2], acc3[4][2];
#pragma unroll
  for (int i = 0; i < 4; ++i)
#pragma unroll
    for (int j = 0; j < 2; ++j) { acc1[i][j] = (f32x4)0.f; acc3[i][j] = (f32x4)0.f; }

  const int Moff = (w & 1) * 64;        // 2 waves over M=128
  const int Noff = (w >> 1) * 32;       // 2 waves over N=64
  const int lr = l & 15;
  const int lg = l >> 4;

  // prologue: issue W(0) into buffer 0 (8 loads)
#pragma unroll
  for (int c = 0; c < 4; ++c) {
    ld_g2l16(w1p + (size_t)c * 16 * HIDDEN, (char*)W1s[0] + c * 4096 + w * 1024);
    ld_g2l16(w3p + (size_t)c * 16 * HIDDEN, (char*)W3s[0] + c * 4096 + w * 1024);
  }

  for (int kb = 0; kb < HIDDEN / 64; ++kb) {
    const int ko = kb * 64;
    const int cb = kb & 1, nb = cb ^ 1;
    // issue X(kb) (4 loads) — Xs reads of step kb-1 finished at that step's end barrier
#pragma unroll
    for (int c = 0; c < 4; ++c)
      ld_g2l16(xp[c] + ko, (char*)Xs + c * 4096 + w * 1024);
    if (kb < HIDDEN / 64 - 1) {
      // issue W(kb+1) into the other buffer (8 loads), stays in flight through compute
#pragma unroll
      for (int c = 0; c < 4; ++c) {
        ld_g2l16(w1p + (size_t)c * 16 * HIDDEN + ko + 64, (char*)W1s[nb] + c * 4096 + w * 1024);
        ld_g2l16(w3p + (size_t)c * 16 * HIDDEN + ko + 64, (char*)W3s[nb] + c * 4096 + w * 1024);
      }
      __builtin_amdgcn_sched_barrier(0);
      asm volatile("s_waitcnt vmcnt(8)" ::: "memory");   // X(kb)+W(kb) landed; W(kb+1) in flight
    } else {
      __builtin_amdgcn_sched_barrier(0);
      asm volatile("s_waitcnt vmcnt(0)" ::: "memory");   // last step: drain
    }
    __builtin_amdgcn_s_barrier();
    __builtin_amdgcn_sched_barrier(0);
#pragma unroll
    for (int s = 0; s < 2; ++s) {
      const int ub = 4 * s + lg;        // A bf16 unit; B fp32 unit pair {2ub, 2ub+1}
      bf16x8 a[4];
#pragma unroll
      for (int mi = 0; mi < 4; ++mi) {
        const int R = Moff + mi * 16 + lr;
        a[mi] = *(const bf16x8*)((const char*)Xs + R * 128 + ((ub ^ (R & 7)) << 4));
      }
#pragma unroll
      for (int ni = 0; ni < 2; ++ni) {
        const int R  = Noff + ni * 16 + lr;
        const int p0 = (2 * ub) ^ (R & 15);     // phys unit holding low half
        float4 lo1 = *(const float4*)((const char*)W1s[cb] + R * 256 + (p0 << 4));
        float4 hi1 = *(const float4*)((const char*)W1s[cb] + R * 256 + ((p0 ^ 1) << 4));
        float4 lo3 = *(const float4*)((const char*)W3s[cb] + R * 256 + (p0 << 4));
        float4 hi3 = *(const float4*)((const char*)W3s[cb] + R * 256 + ((p0 ^ 1) << 4));
        bf16x8 b1 = cvt8b(lo1, hi1);
        bf16x8 b3 = cvt8b(lo3, hi3);
#pragma unroll
        for (int mi = 0; mi < 4; ++mi) {
          acc1[mi][ni] = __builtin_amdgcn_mfma_f32_16x16x32_bf16(a[mi], b1, acc1[mi][ni], 0, 0, 0);
          acc3[mi][ni] = __builtin_amdgcn_mfma_f32_16x16x32_bf16(a[mi], b3, acc3[mi][ni], 0, 0, 0);
        }
      }
    }
    __builtin_amdgcn_sched_barrier(0);
    asm volatile("s_waitcnt lgkmcnt(0)" ::: "memory");   // my LDS reads done before others overwrite
    __builtin_amdgcn_s_barrier();
  }

  const size_t rbase = (size_t)base[e] + (size_t)mt * 128;
#pragma unroll
  for (int mi = 0; mi < 4; ++mi)
#pragma unroll
    for (int ni = 0; ni < 2; ++ni)
#pragma unroll
      for (int j = 0; j < 4; ++j) {
        int row = Moff + mi * 16 + lg * 4 + j;
        int col = nt * 64 + Noff + ni * 16 + lr;
        float s1 = acc1[mi][ni][j], s3 = acc3[mi][ni][j];
        float h = (s1 / (1.f + __expf(-s1))) * s3;      // silu(s1)*s3
        H[(rbase + row) * FFN_DIM + col] = f2bf(h);
      }
}

// ---------------- GEMM2: Y = H W2^T, M=128 x N=64 x BK=64, split-K x2, same pipeline ----------
__global__ __launch_bounds__(256, 3) void gemm2_kernel(
    const unsigned short* __restrict__ H,
    const float* __restrict__ w2f,            // [E][HIDDEN][FFN] fp32
    const int* __restrict__ cnt, const int* __restrict__ base,
    const int* __restrict__ tok, const float* __restrict__ wgt,
    float* __restrict__ out)
{
  const int bid  = blockIdx.x;
  const int e    = bid & 7;
  const int slot = bid >> 3;            // 0..511
  const int mt   = slot & 15;           // 128-row token tile
  const int nt   = (slot >> 4) & 15;    // 64-col hidden tile
  const int sk   = slot >> 8;           // split-K 0..1
  const int n = cnt[e];
  if (mt * 128 >= n) return;
  const int t = threadIdx.x;
  const int w = t >> 6, l = t & 63;

  __shared__ unsigned short Hs[128 * 64];    // 16 KB bf16, single buffer
  __shared__ float W2s[2][64 * 64];          // 2 x 16 KB fp32
  __shared__ int   stok[128];
  __shared__ float swgt[128];

  if (t < 128) {
    int idx = mt * 128 + t;
    int ok = idx < n;
    stok[t] = ok ? tok[e * NTOK + idx] : -1;
    swgt[t] = ok ? wgt[e * NTOK + idx] : 0.f;
  }

  const int xr   = t >> 3;
  const int xkey = ((t & 7) ^ (xr & 7)) << 3;
  const unsigned short* Hp = H + (size_t)(base[e] + mt * 128 + xr) * FFN_DIM
                               + sk * (FFN_DIM / 2) + xkey;
  const int wr   = t >> 4;
  const int wkey = ((t & 15) ^ wr) << 2;
  const float* w2p = w2f + (size_t)e * HIDDEN * FFN_DIM + ((size_t)nt * 64 + wr) * FFN_DIM
                        + sk * (FFN_DIM / 2) + wkey;

  f32x4 acc[4][2];
#pragma unroll
  for (int i = 0; i < 4; ++i)
#pragma unroll
    for (int j = 0; j < 2; ++j) acc[i][j] = (f32x4)0.f;

  const int Moff = (w & 1) * 64;
  const int Noff = (w >> 1) * 32;
  const int lr = l & 15;
  const int lg = l >> 4;

  // prologue: issue W2(0) into buffer 0 (4 loads)
#pragma unroll
  for (int c = 0; c < 4; ++c)
    ld_g2l16(w2p + (size_t)c * 16 * FFN_DIM, (char*)W2s[0] + c * 4096 + w * 1024);

  for (int kb = 0; kb < FFN_DIM / 2 / 64; ++kb) {
    const int ko = kb * 64;
    const int cb = kb & 1, nb = cb ^ 1;
#pragma unroll
    for (int c = 0; c < 4; ++c)
      ld_g2l16(Hp + (size_t)c * 32 * FFN_DIM + ko, (char*)Hs + c * 4096 + w * 1024);
    if (kb < FFN_DIM / 2 / 64 - 1) {
#pragma unroll
      for (int c = 0; c < 4; ++c)
        ld_g2l16(w2p + (size_t)c * 16 * FFN_DIM + ko + 64, (char*)W2s[nb] + c * 4096 + w * 1024);
      __builtin_amdgcn_sched_barrier(0);
      asm volatile("s_waitcnt vmcnt(4)" ::: "memory");   // H(kb)+W2(kb) landed; W2(kb+1) in flight
    } else {
      __builtin_amdgcn_sched_barrier(0);
      asm volatile("s_waitcnt vmcnt(0)" ::: "memory");
    }
    __builtin_amdgcn_s_barrier();
    __builtin_amdgcn_sched_barrier(0);
#pragma unroll
    for (int s = 0; s < 2; ++s) {
      const int ub = 4 * s + lg;
      bf16x8 a[4];
#pragma unroll
      for (int mi = 0; mi < 4; ++mi) {
        const int R = Moff + mi * 16 + lr;
        a[mi] = *(const bf16x8*)((const char*)Hs + R * 128 + ((ub ^ (R & 7)) << 4));
      }
#pragma unroll
      for (int ni = 0; ni < 2; ++ni) {
        const int R  = Noff + ni * 16 + lr;
        const int p0 = (2 * ub) ^ (R & 15);
        float4 lo = *(const float4*)((const char*)W2s[cb] + R * 256 + (p0 << 4));
        float4 hi = *(const float4*)((const char*)W2s[cb] + R * 256 + ((p0 ^ 1) << 4));
        bf16x8 b = cvt8b(lo, hi);
#pragma unroll
        for (int mi = 0; mi < 4; ++mi)
          acc[mi][ni] = __builtin_amdgcn_mfma_f32_16x16x32_bf16(a[mi], b, acc[mi][ni], 0, 0, 0);
      }
    }
    __builtin_amdgcn_sched_barrier(0);
    asm volatile("s_waitcnt lgkmcnt(0)" ::: "memory");
    __builtin_amdgcn_s_barrier();
  }

#pragma unroll
  for (int mi = 0; mi < 4; ++mi)
#pragma unroll
    for (int ni = 0; ni < 2; ++ni)
#pragma unroll
      for (int j = 0; j < 4; ++j) {
        int row = Moff + mi * 16 + lg * 4 + j;
        int tk = stok[row];
        if (tk >= 0) {
          int col = nt * 64 + Noff + ni * 16 + lr;
          atomicAdd(&out[(size_t)tk * HIDDEN + col], swgt[row] * acc[mi][ni][j]);
        }
      }
}

// ================= fp32 fallback path (used only if ws too small) =================
#define TT 12
#define FC 256
#define NCHUNK (FFN_DIM / FC)

__global__ __launch_bounds__(256) void moe_ffn_kernel(
    const float* __restrict__ x,
    const float* __restrict__ w1, const float* __restrict__ w2,
    const float* __restrict__ w3,
    const int* __restrict__ cnt, const int* __restrict__ tok,
    const float* __restrict__ wgt, float* __restrict__ out)
{
  const int e  = blockIdx.y;
  const int n  = cnt[e];
  const int ts = blockIdx.x * TT;
  if (ts >= n) return;
  const int tid = threadIdx.x;

  __shared__ float xs[TT * HIDDEN];
  __shared__ float hc[TT * FC];
  __shared__ int   stok[TT];
  __shared__ float swgt[TT];

  if (tid < TT) {
    int idx = ts + tid;
    int tk  = (idx < n) ? tok[e * NTOK + idx] : -1;
    stok[tid] = tk;
    swgt[tid] = (idx < n) ? wgt[e * NTOK + idx] : 0.f;
  }
  __syncthreads();
#pragma unroll
  for (int i = 0; i < TT; ++i) {
    int tk = stok[i];
    float4 v = make_float4(0.f, 0.f, 0.f, 0.f);
    if (tk >= 0) v = ((const float4*)(x + (size_t)tk * HIDDEN))[tid];
    ((float4*)(xs + i * HIDDEN))[tid] = v;
  }
  __syncthreads();

  const float* w1e = w1 + (size_t)e * FFN_DIM * HIDDEN;
  const float* w3e = w3 + (size_t)e * FFN_DIM * HIDDEN;
  const float* w2e = w2 + (size_t)e * HIDDEN * FFN_DIM;

  float yacc[4][TT];
#pragma unroll
  for (int j = 0; j < 4; ++j)
#pragma unroll
    for (int t = 0; t < TT; ++t) yacc[j][t] = 0.f;

  for (int c = 0; c < NCHUNK; ++c) {
    const int f = c * FC + tid;
    const float4* r1 = (const float4*)(w1e + (size_t)f * HIDDEN);
    const float4* r3 = (const float4*)(w3e + (size_t)f * HIDDEN);
    float a1[TT], a3[TT];
#pragma unroll
    for (int t = 0; t < TT; ++t) { a1[t] = 0.f; a3[t] = 0.f; }
    for (int k = 0; k < HIDDEN / 4; ++k) {
      float4 v1 = r1[k];
      float4 v3 = r3[k];
#pragma unroll
      for (int t = 0; t < TT; ++t) {
        float4 xv = *(const float4*)(xs + t * HIDDEN + 4 * k);
        a1[t] += xv.x * v1.x + xv.y * v1.y + xv.z * v1.z + xv.w * v1.w;
        a3[t] += xv.x * v3.x + xv.y * v3.y + xv.z * v3.z + xv.w * v3.w;
      }
    }
    __syncthreads();
#pragma unroll
    for (int t = 0; t < TT; ++t) {
      float g  = a1[t];
      float sg = g / (1.f + __expf(-g));
      hc[t * FC + tid] = sg * a3[t];
    }
    __syncthreads();
    const float4* r20 = (const float4*)(w2e + (size_t)(tid      ) * FFN_DIM + c * FC);
    const float4* r21 = (const float4*)(w2e + (size_t)(tid + 256) * FFN_DIM + c * FC);
    const float4* r22 = (const float4*)(w2e + (size_t)(tid + 512) * FFN_DIM + c * FC);
    const float4* r23 = (const float4*)(w2e + (size_t)(tid + 768) * FFN_DIM + c * FC);
    for (int k = 0; k < FC / 4; ++k) {
      float4 wv0 = r20[k], wv1 = r21[k], wv2 = r22[k], wv3 = r23[k];
#pragma unroll
      for (int t = 0; t < TT; ++t) {
        float4 hv = *(const float4*)(hc + t * FC + 4 * k);
        yacc[0][t] += hv.x * wv0.x + hv.y * wv0.y + hv.z * wv0.z + hv.w * wv0.w;
        yacc[1][t] += hv.x * wv1.x + hv.y * wv1.y + hv.z * wv1.z + hv.w * wv1.w;
        yacc[2][t] += hv.x * wv2.x + hv.y * wv2.y + hv.z * wv2.z + hv.w * wv2.w;
        yacc[3][t] += hv.x * wv3.x + hv.y * wv3.y + hv.z * wv3.z + hv.w * wv3.w;
      }
    }
  }

#pragma unroll
  for (int t = 0; t < TT; ++t) {
    int tk = stok[t];
    if (tk < 0) continue;
    float wt = swgt[t];
    float* orow = out + (size_t)tk * HIDDEN;
    atomicAdd(orow + tid,       wt * yacc[0][t]);
    atomicAdd(orow + tid + 256, wt * yacc[1][t]);
    atomicAdd(orow + tid + 512, wt * yacc[2][t]);
    atomicAdd(orow + tid + 768, wt * yacc[3][t]);
  }
}

extern "C" void kernel_launch(void* const* d_in, const int* in_sizes, int n_in,
                              void* d_out, int out_size, void* d_ws, size_t ws_size,
                              hipStream_t stream) {
  const float* x  = (const float*)d_in[0];
  const float* gw = (const float*)d_in[1];
  const float* w1 = (const float*)d_in[2];
  const float* w2 = (const float*)d_in[3];
  const float* w3 = (const float*)d_in[4];
  float* out    = (float*)d_out;
  float* logits = out + (size_t)NTOK * HIDDEN;

  char* ws = (char*)d_ws;
  int*   cnt  = (int*)(ws + OFF_CNT);
  int*   base = (int*)(ws + OFF_BASE);
  int*   tokp = (int*)(ws + OFF_TOK);
  float* wgtp = (float*)(ws + OFF_WGT);

  const bool big = (ws_size >= WS_NEED);
  unsigned short* xbf  = big ? (unsigned short*)(ws + OFF_XBF) : (unsigned short*)0;
  unsigned short* Hbuf = big ? (unsigned short*)(ws + OFF_H)   : (unsigned short*)0;

  hipMemsetAsync(out, 0, (size_t)NTOK * HIDDEN * sizeof(float), stream);
  hipMemsetAsync(cnt, 0, NEXP * sizeof(int), stream);

  router_kernel<<<NTOK, 256, 0, stream>>>(x, gw, logits, cnt, tokp, wgtp, xbf);

  if (big) {
    prefix_kernel<<<1, 64, 0, stream>>>(cnt, base);
    gemm1_kernel<<<NEXP * 16 * 32, 256, 0, stream>>>(xbf, w1, w3, cnt, base, tokp, Hbuf);
    gemm2_kernel<<<NEXP * 16 * 16 * 2, 256, 0, stream>>>(Hbuf, w2, cnt, base, tokp, wgtp, out);
  } else {
    dim3 grid((NTOK + TT - 1) / TT, NEXP);
    moe_ffn_kernel<<<grid, 256, 0, stream>>>(x, w1, w2, w3, cnt, tokp, wgtp, out);
  }
}